// Round 11
// baseline (195.337 us; speedup 1.0000x reference)
//
#include <hip/hip_runtime.h>
#include <math.h>

#define BB 16
#define CC 128
#define TT 1024
#define KK 7
#define DK 64
#define NSPLIT 4

typedef float f32x4 __attribute__((ext_vector_type(4)));
typedef short s16x8 __attribute__((ext_vector_type(8)));

__device__ inline short f2bf(float f) {
  union { float f; unsigned u; } v; v.f = f;
  unsigned r = (v.u + 0x7FFFu + ((v.u >> 16) & 1u)) >> 16;
  return (short)r;
}

__device__ inline float bf2f(short s) {
  union { unsigned u; float f; } v;
  v.u = ((unsigned)(unsigned short)s) << 16;
  return v.f;
}

// block-wide (1024 threads) reduce of (s,ss) -> dst[0..1]
__device__ inline void block_partial_1024(float s, float ss, float* dst) {
#pragma unroll
  for (int off = 32; off; off >>= 1) { s += __shfl_xor(s, off); ss += __shfl_xor(ss, off); }
  __shared__ float red[32];
  int w = threadIdx.x >> 6;
  if ((threadIdx.x & 63) == 0) { red[2 * w] = s; red[2 * w + 1] = ss; }
  __syncthreads();
  if (threadIdx.x == 0) {
    for (int i = 1; i < 16; ++i) { s += red[2 * i]; ss += red[2 * i + 1]; }
    dst[0] = s; dst[1] = ss;
  }
}

// reduce n partial (sum,sumsq) pairs for one batch -> sh[0]=mu, sh[1]=rsqrt(var+eps)
__device__ inline void ln_stats_from_parts(const float* part_batch, int n, float* sh) {
  if (threadIdx.x < 64) {
    float s = 0.f, ss = 0.f;
    for (int i = threadIdx.x; i < n; i += 64) { s += part_batch[2 * i]; ss += part_batch[2 * i + 1]; }
#pragma unroll
    for (int off = 32; off; off >>= 1) { s += __shfl_xor(s, off); ss += __shfl_xor(ss, off); }
    if (threadIdx.x == 0) {
      const float invN = 1.f / (float)(CC * TT);
      float mu = s * invN;
      sh[0] = mu;
      sh[1] = rsqrtf(ss * invN - mu * mu + 1e-5f);
    }
  }
  __syncthreads();
}

// ---- merged: weight prep (blocks 0..447) + LN0 partials of x+pos (blocks 448..959) ----
__global__ __launch_bounds__(256) void k_prep0(const float* __restrict__ pww,
                                               const float* __restrict__ Wq,
                                               const float* __restrict__ Wk,
                                               const float* __restrict__ Wv,
                                               const float* __restrict__ Wo,
                                               const float* __restrict__ fcw,
                                               const float* __restrict__ x,
                                               short* __restrict__ pwwb,
                                               short* __restrict__ wqkvb,
                                               short* __restrict__ wo2b,
                                               short* __restrict__ fcwb,
                                               float* __restrict__ part0) {
  if (blockIdx.x < 448) {
    int i = blockIdx.x * 256 + threadIdx.x;  // 114688
    if (i < 65536) { pwwb[i] = f2bf(pww[i]); return; }
    i -= 65536;
    if (i < 24576) {  // wqkvb[m][c] = W{q,k,v}[c][m&63]
      int m = i >> 7, c = i & 127;
      int sel = m >> 6, d = m & 63;
      const float* srcp = sel == 0 ? Wq : (sel == 1 ? Wk : Wv);
      wqkvb[i] = f2bf(srcp[c * DK + d]);
      return;
    }
    i -= 24576;
    if (i < 8192) {  // wo2b[o][d] = Wo[d][o] + Wo[d+64][o]
      int o = i >> 6, d = i & 63;
      wo2b[i] = f2bf(Wo[d * CC + o] + Wo[(d + 64) * CC + o]);
      return;
    }
    i -= 8192;
    fcwb[i] = f2bf(fcw[i]);
    return;
  }
  // partials of x+pos: 512 blocks x 4 waves, one (b,c) row per wave
  int w = threadIdx.x >> 6, lane = threadIdx.x & 63;
  int bc = (blockIdx.x - 448) * 4 + w;  // 0..2047
  int c = bc & (CC - 1);
  float freq = expf(-((float)(c & ~1) * (1.f / (float)CC)) * 9.210340371976184f);
  float ph = (c & 1) ? 1.5707963267948966f : 0.f;
  const float* xr = x + (size_t)bc * TT;
  float s = 0.f, ss = 0.f;
#pragma unroll
  for (int k = 0; k < 4; ++k) {
    int t = (k * 64 + lane) * 4;
    float4 v = *(const float4*)(xr + t);
    v.x += sinf((float)(t + 0) * freq + ph);
    v.y += sinf((float)(t + 1) * freq + ph);
    v.z += sinf((float)(t + 2) * freq + ph);
    v.w += sinf((float)(t + 3) * freq + ph);
    s += v.x + v.y + v.z + v.w;
    ss += v.x * v.x + v.y * v.y + v.z * v.z + v.w * v.w;
  }
#pragma unroll
  for (int off = 32; off; off >>= 1) { s += __shfl_xor(s, off); ss += __shfl_xor(ss, off); }
  if (lane == 0) { part0[(size_t)bc * 2] = s; part0[(size_t)bc * 2 + 1] = ss; }
}

// ------- dsconv (32-col tiles, 1024 threads = 16 waves): [ADD_POS] [LN-in] depthwise ->
//         MFMA pointwise (8x2 wave grid) + relu + [LN-res] residual; coalesced out -------
template <bool LN_IN, bool LN_RES, bool ADD_POS>
__global__ __launch_bounds__(1024) void k_dsconv(const float* __restrict__ in,
                                                 const float* __restrict__ lng,
                                                 const float* __restrict__ lnb,
                                                 const float* __restrict__ part_in, int npart,
                                                 const float* __restrict__ dww,
                                                 const float* __restrict__ dwb,
                                                 const short* __restrict__ pwwb,
                                                 const float* __restrict__ pwb,
                                                 float* __restrict__ out,
                                                 float* __restrict__ part_out) {
  int tile = blockIdx.x & 31, b = blockIdx.x >> 5;
  int t0 = tile * 32;
  __shared__ float stats[2];
  __shared__ float xs[CC][41];                   // window t0-4 .. t0+35 (40 used)
  __shared__ float xr2[CC][33];                  // raw copy (LN_IN) then output staging
  __shared__ __align__(16) short Dt[32][136];
  ln_stats_from_parts(part_in + (size_t)b * npart * 2, npart, stats);
  float mu = stats[0], rs = stats[1];

  for (int i = threadIdx.x; i < CC * 10; i += 1024) {
    int c = i / 10, q = i - c * 10;
    int tb = t0 - 4 + q * 4;
    const float* rowp = in + ((size_t)b * CC + c) * TT;
    float freq = 0.f, ph = 0.f;
    if (ADD_POS) {
      freq = expf(-((float)(c & ~1) * (1.f / (float)CC)) * 9.210340371976184f);
      ph = (c & 1) ? 1.5707963267948966f : 0.f;
    }
    float r0, r1, r2, r3, o0, o1, o2, o3;
    bool full = (tb >= 0) && (tb + 4 <= TT);
    if (full) {
      float4 v = *(const float4*)(rowp + tb);
      if (ADD_POS) {
        v.x += sinf((float)(tb + 0) * freq + ph);
        v.y += sinf((float)(tb + 1) * freq + ph);
        v.z += sinf((float)(tb + 2) * freq + ph);
        v.w += sinf((float)(tb + 3) * freq + ph);
      }
      r0 = v.x; r1 = v.y; r2 = v.z; r3 = v.w;
      o0 = r0; o1 = r1; o2 = r2; o3 = r3;
      if (LN_IN) {
        float4 g = *(const float4*)(lng + (size_t)c * TT + tb);
        float4 bv = *(const float4*)(lnb + (size_t)c * TT + tb);
        o0 = (r0 - mu) * rs * g.x + bv.x;
        o1 = (r1 - mu) * rs * g.y + bv.y;
        o2 = (r2 - mu) * rs * g.z + bv.z;
        o3 = (r3 - mu) * rs * g.w + bv.w;
      }
    } else {
      float rr[4], oo[4];
#pragma unroll
      for (int k = 0; k < 4; ++k) {
        int t = tb + k;
        bool inb = (t >= 0) && (t < TT);
        float rv = 0.f;
        if (inb) {
          rv = rowp[t];
          if (ADD_POS) rv += sinf((float)t * freq + ph);
        }
        rr[k] = rv;
        float ov = rv;
        if (LN_IN && inb)
          ov = (rv - mu) * rs * lng[(size_t)c * TT + t] + lnb[(size_t)c * TT + t];
        oo[k] = ov;
      }
      r0 = rr[0]; r1 = rr[1]; r2 = rr[2]; r3 = rr[3];
      o0 = oo[0]; o1 = oo[1]; o2 = oo[2]; o3 = oo[3];
    }
    if (LN_IN && q >= 1 && q <= 8) {
      int tl = (q - 1) * 4;
      xr2[c][tl] = r0; xr2[c][tl + 1] = r1; xr2[c][tl + 2] = r2; xr2[c][tl + 3] = r3;
    }
    int base = q * 4;
    xs[c][base] = o0; xs[c][base + 1] = o1; xs[c][base + 2] = o2; xs[c][base + 3] = o3;
  }
  __syncthreads();
  for (int i = threadIdx.x; i < 32 * CC; i += 1024) {
    int t = i >> 7, c = i & 127;
    float a = dwb[c];
#pragma unroll
    for (int j = 0; j < KK; ++j) a += dww[c * KK + j] * xs[c][t + j + 1];
    Dt[t][c] = f2bf(a);
  }
  __syncthreads();

  int w = threadIdx.x >> 6, lane = threadIdx.x & 63;  // 16 waves: (wr 0..7) x (wc 0..1)
  int wr = w >> 1, wc = w & 1;
  int lo = lane & 15, hi = lane >> 4;
  f32x4 acc;
  acc[0] = 0.f; acc[1] = 0.f; acc[2] = 0.f; acc[3] = 0.f;
#pragma unroll
  for (int ks = 0; ks < 4; ++ks) {
    s16x8 b0 = *(const s16x8*)&Dt[wc * 16 + lo][ks * 32 + hi * 8];
    s16x8 a0 = *(const s16x8*)&pwwb[(size_t)(wr * 16 + lo) * CC + ks * 32 + hi * 8];
    acc = __builtin_amdgcn_mfma_f32_16x16x32_bf16(a0, b0, acc, 0, 0, 0);
  }

  float s = 0.f, ss = 0.f;
#pragma unroll
  for (int r = 0; r < 4; ++r) {
    int row = wr * 16 + hi * 4 + r;
    int tl = wc * 16 + lo;
    int t = t0 + tl;
    float v = acc[r] + pwb[row];
    v = v > 0.f ? v : 0.f;
    float rv;
    if (LN_RES) {
      float raw = xs[row][tl + 4];
      rv = (raw - mu) * rs * lng[row * TT + t] + lnb[row * TT + t];
    } else if (LN_IN) {
      rv = xr2[row][tl];
    } else {
      rv = xs[row][tl + 4];
    }
    v += rv;
    xr2[row][tl] = v;
    s += v; ss += v * v;
  }
  __syncthreads();
  {
    int u = threadIdx.x;  // exactly 1024 = 128 rows x 8 float4
    int c = u >> 3, q = u & 7;
    float4 o4;
    o4.x = xr2[c][q * 4]; o4.y = xr2[c][q * 4 + 1];
    o4.z = xr2[c][q * 4 + 2]; o4.w = xr2[c][q * 4 + 3];
    *(float4*)(out + ((size_t)b * CC + c) * TT + t0 + q * 4) = o4;
  }
  block_partial_1024(s, ss, part_out + (size_t)blockIdx.x * 2);
}

// ---------------- q,k,v projections (32-col tiles, 1024 threads) ----------------
__global__ __launch_bounds__(1024) void k_qkv(const float* __restrict__ in,
                                              const float* __restrict__ lng,
                                              const float* __restrict__ lnb,
                                              const float* __restrict__ part_in,
                                              const short* __restrict__ wqkvb,
                                              short* __restrict__ q,
                                              short* __restrict__ k,
                                              short* __restrict__ vt) {
  int tile = blockIdx.x & 31, b = blockIdx.x >> 5;
  int t0 = tile * 32;
  __shared__ float stats[2];
  __shared__ __align__(16) short Dt[32][136];
  __shared__ __align__(16) short stgQ[32 * 64];
  __shared__ __align__(16) short stgK[32 * 64];
  __shared__ __align__(16) short stgV[64][40];
  ln_stats_from_parts(part_in + (size_t)b * 64, 32, stats);
  float mu = stats[0], rs = stats[1];
  {
    int i = threadIdx.x;  // exactly CC*8 = 1024
    int c = i >> 3, qq = i & 7;
    int t = qq * 4;
    size_t off = (size_t)c * TT + t0 + t;
    float4 v = *(const float4*)(in + (size_t)b * CC * TT + off);
    float4 g = *(const float4*)(lng + off);
    float4 bb = *(const float4*)(lnb + off);
    Dt[t + 0][c] = f2bf((v.x - mu) * rs * g.x + bb.x);
    Dt[t + 1][c] = f2bf((v.y - mu) * rs * g.y + bb.y);
    Dt[t + 2][c] = f2bf((v.z - mu) * rs * g.z + bb.z);
    Dt[t + 3][c] = f2bf((v.w - mu) * rs * g.w + bb.w);
  }
  __syncthreads();

  int w = threadIdx.x >> 6, lane = threadIdx.x & 63;  // waves 0..11 active: rows w*16 of 192
  int lo = lane & 15, hi = lane >> 4;
  if (w < 12) {
    f32x4 acc[2];
#pragma unroll
    for (int nt = 0; nt < 2; ++nt) { acc[nt][0] = 0.f; acc[nt][1] = 0.f; acc[nt][2] = 0.f; acc[nt][3] = 0.f; }
#pragma unroll
    for (int ks = 0; ks < 4; ++ks) {
      s16x8 b0 = *(const s16x8*)&Dt[lo][ks * 32 + hi * 8];
      s16x8 b1 = *(const s16x8*)&Dt[16 + lo][ks * 32 + hi * 8];
      s16x8 a = *(const s16x8*)&wqkvb[(size_t)(w * 16 + lo) * CC + ks * 32 + hi * 8];
      acc[0] = __builtin_amdgcn_mfma_f32_16x16x32_bf16(a, b0, acc[0], 0, 0, 0);
      acc[1] = __builtin_amdgcn_mfma_f32_16x16x32_bf16(a, b1, acc[1], 0, 0, 0);
    }
#pragma unroll
    for (int nt = 0; nt < 2; ++nt) {
      int m0 = w * 16 + hi * 4;   // wave-uniform tensor selection (16-row bands)
      int tl = nt * 16 + lo;
      short pv[4];
#pragma unroll
      for (int j = 0; j < 4; ++j) pv[j] = f2bf(acc[nt][j]);
      if (m0 < 64) {
        *(short4*)&stgQ[tl * 64 + m0] = make_short4(pv[0], pv[1], pv[2], pv[3]);
      } else if (m0 < 128) {
        *(short4*)&stgK[tl * 64 + (m0 - 64)] = make_short4(pv[0], pv[1], pv[2], pv[3]);
      } else {
        int d = m0 - 128;
#pragma unroll
        for (int j = 0; j < 4; ++j) stgV[d + j][tl] = pv[j];
      }
    }
  }
  __syncthreads();
  {
    if (threadIdx.x < 256) {
      int t = threadIdx.x >> 3, ch = threadIdx.x & 7;   // 32 rows x 8 chunks
      *(s16x8*)(q + ((size_t)b * TT + t0 + t) * DK + ch * 8) = *(const s16x8*)&stgQ[t * 64 + ch * 8];
    } else if (threadIdx.x < 512) {
      int i = threadIdx.x - 256;
      int t = i >> 3, ch = i & 7;
      *(s16x8*)(k + ((size_t)b * TT + t0 + t) * DK + ch * 8) = *(const s16x8*)&stgK[t * 64 + ch * 8];
    } else if (threadIdx.x < 768) {
      int i = threadIdx.x - 512;
      int d = i >> 2, cv = i & 3;   // 64 rows x 4 chunks
      *(s16x8*)(vt + ((size_t)b * DK + d) * TT + t0 + cv * 8) = *(const s16x8*)&stgV[d][cv * 8];
    }
  }
}

// ---------------- flash attention, split-K; register-double-buffered K/V staging ----------------
__global__ __launch_bounds__(128) void k_attn(const short* __restrict__ qb,
                                              const short* __restrict__ kbuf,
                                              const short* __restrict__ vtb,
                                              const float* __restrict__ mask,
                                              short* __restrict__ pacch,
                                              float* __restrict__ pml) {
  int sp = blockIdx.x & (NSPLIT - 1);
  int qt = (blockIdx.x >> 2) & 31;
  int b = blockIdx.x >> 7;
  int w = threadIdx.x >> 6, lane = threadIdx.x & 63;
  int lo = lane & 15, hi = lane >> 4;

  __shared__ __align__(16) short ks[64][72];
  __shared__ __align__(16) short vt[64][72];
  __shared__ __align__(16) short ps[2][16][68];
  __shared__ float ms[64];

  const short* qp = qb + ((size_t)b * TT + qt * 32 + w * 16 + lo) * DK + hi * 8;
  s16x8 aq0 = *(const s16x8*)qp;
  s16x8 aq1 = *(const s16x8*)(qp + 32);

  f32x4 acc[4];
  float m_i[4], l_i[4];
#pragma unroll
  for (int r = 0; r < 4; ++r) {
    m_i[r] = -3.0e38f; l_i[r] = 0.f;
#pragma unroll
    for (int nt = 0; nt < 4; ++nt) acc[nt][r] = 0.f;
  }
  const float scale = 0.125f;
  const int kb0 = sp * (TT / 64 / NSPLIT);   // 4 iterations

  s16x8 kreg[4], vreg[4];
#pragma unroll
  for (int j = 0; j < 4; ++j) {
    int i = threadIdx.x + j * 128;
    int r = i >> 3, ch = i & 7;
    kreg[j] = *(const s16x8*)(kbuf + ((size_t)b * TT + kb0 * 64 + r) * DK + ch * 8);
    vreg[j] = *(const s16x8*)(vtb + ((size_t)b * DK + r) * TT + kb0 * 64 + ch * 8);
  }

  for (int it = 0; it < 4; ++it) {
    int kb2 = kb0 + it;
    __syncthreads();
#pragma unroll
    for (int j = 0; j < 4; ++j) {
      int i = threadIdx.x + j * 128;
      int r = i >> 3, ch = i & 7;
      *(s16x8*)&ks[r][ch * 8] = kreg[j];
      *(s16x8*)&vt[r][ch * 8] = vreg[j];
    }
    if (threadIdx.x < 64) ms[threadIdx.x] = mask[(size_t)b * TT + kb2 * 64 + threadIdx.x];
    __syncthreads();
    if (it < 3) {
#pragma unroll
      for (int j = 0; j < 4; ++j) {
        int i = threadIdx.x + j * 128;
        int r = i >> 3, ch = i & 7;
        kreg[j] = *(const s16x8*)(kbuf + ((size_t)b * TT + (kb2 + 1) * 64 + r) * DK + ch * 8);
        vreg[j] = *(const s16x8*)(vtb + ((size_t)b * DK + r) * TT + (kb2 + 1) * 64 + ch * 8);
      }
    }

    f32x4 sc[4];
#pragma unroll
    for (int nt = 0; nt < 4; ++nt) {
      f32x4 z; z[0] = 0.f; z[1] = 0.f; z[2] = 0.f; z[3] = 0.f;
      s16x8 bk0 = *(const s16x8*)&ks[nt * 16 + lo][hi * 8];
      s16x8 bk1 = *(const s16x8*)&ks[nt * 16 + lo][32 + hi * 8];
      z = __builtin_amdgcn_mfma_f32_16x16x32_bf16(aq0, bk0, z, 0, 0, 0);
      z = __builtin_amdgcn_mfma_f32_16x16x32_bf16(aq1, bk1, z, 0, 0, 0);
      sc[nt] = z;
    }
#pragma unroll
    for (int nt = 0; nt < 4; ++nt) {
      float mv = ms[nt * 16 + lo];
      float addv = (1.f - mv) * -1e30f;
#pragma unroll
      for (int r = 0; r < 4; ++r) sc[nt][r] = sc[nt][r] * scale * mv + addv;
    }
    float alpha[4];
#pragma unroll
    for (int r = 0; r < 4; ++r) {
      float m0 = fmaxf(fmaxf(sc[0][r], sc[1][r]), fmaxf(sc[2][r], sc[3][r]));
#pragma unroll
      for (int off = 1; off < 16; off <<= 1) m0 = fmaxf(m0, __shfl_xor(m0, off));
      float mn = fmaxf(m_i[r], m0);
      alpha[r] = __expf(m_i[r] - mn);
      m_i[r] = mn;
    }
    float psum[4] = {0.f, 0.f, 0.f, 0.f};
#pragma unroll
    for (int nt = 0; nt < 4; ++nt)
#pragma unroll
      for (int r = 0; r < 4; ++r) {
        float p = __expf(sc[nt][r] - m_i[r]);
        psum[r] += p;
        ps[w][hi * 4 + r][nt * 16 + lo] = f2bf(p);
      }
#pragma unroll
    for (int r = 0; r < 4; ++r) {
      float sum = psum[r];
#pragma unroll
      for (int off = 1; off < 16; off <<= 1) sum += __shfl_xor(sum, off);
      l_i[r] = l_i[r] * alpha[r] + sum;
    }
#pragma unroll
    for (int nt = 0; nt < 4; ++nt)
#pragma unroll
      for (int r = 0; r < 4; ++r) acc[nt][r] *= alpha[r];

    s16x8 ap0 = *(const s16x8*)&ps[w][lo][hi * 8];
    s16x8 ap1 = *(const s16x8*)&ps[w][lo][32 + hi * 8];
#pragma unroll
    for (int nt = 0; nt < 4; ++nt) {
      s16x8 bv0 = *(const s16x8*)&vt[nt * 16 + lo][hi * 8];
      s16x8 bv1 = *(const s16x8*)&vt[nt * 16 + lo][32 + hi * 8];
      acc[nt] = __builtin_amdgcn_mfma_f32_16x16x32_bf16(ap0, bv0, acc[nt], 0, 0, 0);
      acc[nt] = __builtin_amdgcn_mfma_f32_16x16x32_bf16(ap1, bv1, acc[nt], 0, 0, 0);
    }
  }
  __syncthreads();
  short* pc = &ks[0][0];  // 32 x 64 shorts
#pragma unroll
  for (int r = 0; r < 4; ++r) {
    int row = w * 16 + hi * 4 + r;
#pragma unroll
    for (int nt = 0; nt < 4; ++nt) pc[row * 64 + nt * 16 + lo] = f2bf(acc[nt][r]);
    if (lo == 0) {
      size_t mb = (((size_t)b * TT + qt * 32 + row) * NSPLIT + sp) * 2;
      pml[mb] = m_i[r];
      pml[mb + 1] = l_i[r];
    }
  }
  __syncthreads();
  for (int u = threadIdx.x; u < 256; u += 128) {
    int row = u >> 3, ch = u & 7;
    size_t pb = (((size_t)b * TT + qt * 32 + row) * NSPLIT + sp) * DK;
    *(s16x8*)(pacch + pb + ch * 8) = *(const s16x8*)&pc[row * 64 + ch * 8];
  }
}

// ------- fused: split-K combine (LDS) + heads@Wo2 MFMA + residual (1024 threads) -------
__global__ __launch_bounds__(1024) void k_attnout2(const short* __restrict__ pacch,
                                                   const float* __restrict__ pml,
                                                   const float* __restrict__ mask,
                                                   const short* __restrict__ wo2b,
                                                   const float* __restrict__ res,
                                                   float* __restrict__ out,
                                                   float* __restrict__ part_out) {
  int tile = blockIdx.x & 31, b = blockIdx.x >> 5;
  int t0 = tile * 32;
  __shared__ __align__(16) short Ht[32][72];
  __shared__ float ot[128][33];
  if (threadIdx.x < 256) {
    int i = threadIdx.x;          // 32 rows x 8 chunks of 8 d
    int tr = i >> 3, q = i & 7;
    size_t rb = (size_t)b * TT + t0 + tr;
    s16x8 pvv[NSPLIT];
#pragma unroll
    for (int s = 0; s < NSPLIT; ++s)
      pvv[s] = *(const s16x8*)(pacch + (rb * NSPLIT + s) * DK + q * 8);
    float m[NSPLIT], l[NSPLIT];
#pragma unroll
    for (int s = 0; s < NSPLIT; ++s) {
      m[s] = pml[(rb * NSPLIT + s) * 2];
      l[s] = pml[(rb * NSPLIT + s) * 2 + 1];
    }
    float M = fmaxf(fmaxf(m[0], m[1]), fmaxf(m[2], m[3]));
    float wgt[NSPLIT], L = 0.f;
#pragma unroll
    for (int s = 0; s < NSPLIT; ++s) { wgt[s] = __expf(m[s] - M); L += wgt[s] * l[s]; }
    float inv = mask[rb] / L;
    float o[8] = {0.f, 0.f, 0.f, 0.f, 0.f, 0.f, 0.f, 0.f};
#pragma unroll
    for (int s = 0; s < NSPLIT; ++s) {
#pragma unroll
      for (int j = 0; j < 8; ++j) o[j] += wgt[s] * bf2f(pvv[s][j]);
    }
    short h[8];
#pragma unroll
    for (int j = 0; j < 8; ++j) h[j] = f2bf(o[j] * inv);
    *(s16x8*)&Ht[tr][q * 8] = *(const s16x8*)h;
  }
  __syncthreads();

  int w = threadIdx.x >> 6, lane = threadIdx.x & 63;  // 16 waves: (wr 0..7) x (wc 0..1)
  int wr = w >> 1, wc = w & 1;
  int lo = lane & 15, hi = lane >> 4;
  f32x4 acc;
  acc[0] = 0.f; acc[1] = 0.f; acc[2] = 0.f; acc[3] = 0.f;
#pragma unroll
  for (int ks = 0; ks < 2; ++ks) {
    s16x8 b0 = *(const s16x8*)&Ht[wc * 16 + lo][ks * 32 + hi * 8];
    s16x8 a0 = *(const s16x8*)&wo2b[(size_t)(wr * 16 + lo) * DK + ks * 32 + hi * 8];
    acc = __builtin_amdgcn_mfma_f32_16x16x32_bf16(a0, b0, acc, 0, 0, 0);
  }
  float s = 0.f, ss = 0.f;
#pragma unroll
  for (int r = 0; r < 4; ++r) {
    int row = wr * 16 + hi * 4 + r;
    int tl = wc * 16 + lo;
    size_t idx = ((size_t)b * CC + row) * TT + t0 + tl;
    float v = acc[r] + res[idx];
    ot[row][tl] = v;
    s += v; ss += v * v;
  }
  __syncthreads();
  {
    int u = threadIdx.x;  // exactly 1024
    int c = u >> 3, q = u & 7;
    float4 o4;
    o4.x = ot[c][q * 4]; o4.y = ot[c][q * 4 + 1];
    o4.z = ot[c][q * 4 + 2]; o4.w = ot[c][q * 4 + 3];
    *(float4*)(out + ((size_t)b * CC + c) * TT + t0 + q * 4) = o4;
  }
  block_partial_1024(s, ss, part_out + (size_t)blockIdx.x * 2);
}

// ---------------- FC (32-col tiles, 1024 threads): LN + MFMA + relu + residual ----------------
__global__ __launch_bounds__(1024) void k_fc(const float* __restrict__ in,
                                             const float* __restrict__ lng,
                                             const float* __restrict__ lnb,
                                             const float* __restrict__ part_in,
                                             const short* __restrict__ fcwb,
                                             const float* __restrict__ fb,
                                             float* __restrict__ out) {
  int tile = blockIdx.x & 31, b = blockIdx.x >> 5;
  int t0 = tile * 32;
  __shared__ float stats[2];
  __shared__ float xr2[CC][33];
  __shared__ __align__(16) short Dt[32][136];
  ln_stats_from_parts(part_in + (size_t)b * 64, 32, stats);
  float mu = stats[0], rs = stats[1];
  {
    int i = threadIdx.x;  // exactly CC*8 = 1024
    int c = i >> 3, q = i & 7;
    int t = q * 4;
    size_t off = (size_t)c * TT + t0 + t;
    float4 v = *(const float4*)(in + (size_t)b * CC * TT + off);
    float4 g = *(const float4*)(lng + off);
    float4 bb = *(const float4*)(lnb + off);
    xr2[c][t] = v.x; xr2[c][t + 1] = v.y; xr2[c][t + 2] = v.z; xr2[c][t + 3] = v.w;
    Dt[t + 0][c] = f2bf((v.x - mu) * rs * g.x + bb.x);
    Dt[t + 1][c] = f2bf((v.y - mu) * rs * g.y + bb.y);
    Dt[t + 2][c] = f2bf((v.z - mu) * rs * g.z + bb.z);
    Dt[t + 3][c] = f2bf((v.w - mu) * rs * g.w + bb.w);
  }
  __syncthreads();

  int w = threadIdx.x >> 6, lane = threadIdx.x & 63;  // 16 waves: (wr 0..7) x (wc 0..1)
  int wr = w >> 1, wc = w & 1;
  int lo = lane & 15, hi = lane >> 4;
  f32x4 acc;
  acc[0] = 0.f; acc[1] = 0.f; acc[2] = 0.f; acc[3] = 0.f;
#pragma unroll
  for (int ks = 0; ks < 4; ++ks) {
    s16x8 b0 = *(const s16x8*)&Dt[wc * 16 + lo][ks * 32 + hi * 8];
    s16x8 a0 = *(const s16x8*)&fcwb[(size_t)(wr * 16 + lo) * CC + ks * 32 + hi * 8];
    acc = __builtin_amdgcn_mfma_f32_16x16x32_bf16(a0, b0, acc, 0, 0, 0);
  }
#pragma unroll
  for (int r = 0; r < 4; ++r) {
    int row = wr * 16 + hi * 4 + r;
    int tl = wc * 16 + lo;
    float v = acc[r] + fb[row];
    v = v > 0.f ? v : 0.f;
    xr2[row][tl] = v + xr2[row][tl];
  }
  __syncthreads();
  {
    int u = threadIdx.x;  // exactly 1024
    int c = u >> 3, q = u & 7;
    float4 o4;
    o4.x = xr2[c][q * 4]; o4.y = xr2[c][q * 4 + 1];
    o4.z = xr2[c][q * 4 + 2]; o4.w = xr2[c][q * 4 + 3];
    *(float4*)(out + ((size_t)b * CC + c) * TT + t0 + q * 4) = o4;
  }
}

extern "C" void kernel_launch(void* const* d_in, const int* in_sizes, int n_in,
                              void* d_out, int out_size, void* d_ws, size_t ws_size,
                              hipStream_t stream) {
  const float* x    = (const float*)d_in[0];
  const float* mask = (const float*)d_in[1];
  const float* dww  = (const float*)d_in[2];
  const float* dwb  = (const float*)d_in[3];
  const float* pww  = (const float*)d_in[4];
  const float* pwb  = (const float*)d_in[5];
  const float* n0g  = (const float*)d_in[6];
  const float* n0b  = (const float*)d_in[7];
  const float* nsg  = (const float*)d_in[8];
  const float* nsb  = (const float*)d_in[9];
  const float* neg_ = (const float*)d_in[10];
  const float* neb  = (const float*)d_in[11];
  const float* Wq   = (const float*)d_in[12];
  const float* Wk   = (const float*)d_in[13];
  const float* Wv   = (const float*)d_in[14];
  const float* Wo   = (const float*)d_in[15];
  const float* fcw  = (const float*)d_in[16];
  const float* fcb  = (const float*)d_in[17];
  float* out = (float*)d_out;

  float* W = (float*)d_ws;
  const size_t NBCT = (size_t)BB * CC * TT;
  const size_t NBTD = (size_t)BB * TT * DK;
  const size_t CT = (size_t)CC * TT;
  float* O     = W;
  float* S     = W + NBCT;
  float* PART0 = W + 2 * NBCT;           // 16*128 pairs
  float* PARTS = PART0 + 4096;           // 5 stages x 16*32 pairs
  float* PML   = PARTS + 5 * 1024;       // BB*TT*NSPLIT*2
  short* QB    = (short*)(PML + (size_t)BB * TT * NSPLIT * 2);
  short* KB    = QB + NBTD;
  short* VT    = KB + NBTD;
  short* PACCH = VT + NBTD;              // BB*TT*NSPLIT*DK bf16
  short* PWWB  = PACCH + NBTD * NSPLIT;  // 4*128*128
  short* WQKVB = PWWB + 65536;           // 192*128
  short* WO2B  = WQKVB + 24576;          // 128*64
  short* FCWB  = WO2B + 8192;            // 128*128

  k_prep0<<<960, 256, 0, stream>>>(pww, Wq, Wk, Wv, Wo, fcw, x,
                                   PWWB, WQKVB, WO2B, FCWB, PART0);
  // iter0: input = x (+pos inline), residual = LN0(x+pos)
  k_dsconv<false, true, true><<<BB * 32, 1024, 0, stream>>>(
      x, n0g, n0b, PART0, 128, dww, dwb, PWWB, pwb, S, PARTS);
  k_dsconv<true, false, false><<<BB * 32, 1024, 0, stream>>>(
      S, nsg + 0 * CT, nsb + 0 * CT, PARTS, 32,
      dww + 1 * CC * KK, dwb + 1 * CC, PWWB + 1 * CC * CC, pwb + 1 * CC, O, PARTS + 1024);
  k_dsconv<true, false, false><<<BB * 32, 1024, 0, stream>>>(
      O, nsg + 1 * CT, nsb + 1 * CT, PARTS + 1024, 32,
      dww + 2 * CC * KK, dwb + 2 * CC, PWWB + 2 * CC * CC, pwb + 2 * CC, S, PARTS + 2048);
  k_dsconv<true, false, false><<<BB * 32, 1024, 0, stream>>>(
      S, nsg + 2 * CT, nsb + 2 * CT, PARTS + 2048, 32,
      dww + 3 * CC * KK, dwb + 3 * CC, PWWB + 3 * CC * CC, pwb + 3 * CC, O, PARTS + 3072);
  // qkv: input = LN_3(O)
  k_qkv<<<BB * 32, 1024, 0, stream>>>(O, nsg + 3 * CT, nsb + 3 * CT, PARTS + 3072,
                                      WQKVB, QB, KB, VT);
  k_attn<<<BB * 32 * NSPLIT, 128, 0, stream>>>(QB, KB, VT, mask, PACCH, PML);
  // fused combine + attnout: residual = O raw
  k_attnout2<<<BB * 32, 1024, 0, stream>>>(PACCH, PML, mask, WO2B, O, S, PARTS + 4096);
  // fc: input = LN_e(S), residual = S raw
  k_fc<<<BB * 32, 1024, 0, stream>>>(S, neg_, neb, PARTS + 4096, FCWB, fcb, out);
}

// Round 12
// 183.868 us; speedup vs baseline: 1.0624x; 1.0624x over previous
//
#include <hip/hip_runtime.h>
#include <math.h>

#define BB 16
#define CC 128
#define TT 1024
#define KK 7
#define DK 64
#define NSPLIT 4

typedef float f32x4 __attribute__((ext_vector_type(4)));
typedef short s16x8 __attribute__((ext_vector_type(8)));

__device__ inline short f2bf(float f) {
  union { float f; unsigned u; } v; v.f = f;
  unsigned r = (v.u + 0x7FFFu + ((v.u >> 16) & 1u)) >> 16;
  return (short)r;
}

__device__ inline float bf2f(short s) {
  union { unsigned u; float f; } v;
  v.u = ((unsigned)(unsigned short)s) << 16;
  return v.f;
}

// block-wide (512 threads) reduce of (s,ss) -> dst[0..1]
__device__ inline void block_partial_512(float s, float ss, float* dst) {
#pragma unroll
  for (int off = 32; off; off >>= 1) { s += __shfl_xor(s, off); ss += __shfl_xor(ss, off); }
  __shared__ float red[16];
  int w = threadIdx.x >> 6;
  if ((threadIdx.x & 63) == 0) { red[2 * w] = s; red[2 * w + 1] = ss; }
  __syncthreads();
  if (threadIdx.x == 0) {
    for (int i = 1; i < 8; ++i) { s += red[2 * i]; ss += red[2 * i + 1]; }
    dst[0] = s; dst[1] = ss;
  }
}

// reduce n partial (sum,sumsq) pairs for one batch -> sh[0]=mu, sh[1]=rsqrt(var+eps)
__device__ inline void ln_stats_from_parts(const float* part_batch, int n, float* sh) {
  if (threadIdx.x < 64) {
    float s = 0.f, ss = 0.f;
    for (int i = threadIdx.x; i < n; i += 64) { s += part_batch[2 * i]; ss += part_batch[2 * i + 1]; }
#pragma unroll
    for (int off = 32; off; off >>= 1) { s += __shfl_xor(s, off); ss += __shfl_xor(ss, off); }
    if (threadIdx.x == 0) {
      const float invN = 1.f / (float)(CC * TT);
      float mu = s * invN;
      sh[0] = mu;
      sh[1] = rsqrtf(ss * invN - mu * mu + 1e-5f);
    }
  }
  __syncthreads();
}

// ---- merged: weight prep (blocks 0..447) + LN0 partials of x+pos (blocks 448..959) ----
__global__ __launch_bounds__(256) void k_prep0(const float* __restrict__ pww,
                                               const float* __restrict__ Wq,
                                               const float* __restrict__ Wk,
                                               const float* __restrict__ Wv,
                                               const float* __restrict__ Wo,
                                               const float* __restrict__ fcw,
                                               const float* __restrict__ x,
                                               short* __restrict__ pwwb,
                                               short* __restrict__ wqkvb,
                                               short* __restrict__ wo2b,
                                               short* __restrict__ fcwb,
                                               float* __restrict__ part0) {
  if (blockIdx.x < 448) {
    int i = blockIdx.x * 256 + threadIdx.x;  // 114688
    if (i < 65536) { pwwb[i] = f2bf(pww[i]); return; }
    i -= 65536;
    if (i < 24576) {  // wqkvb[m][c] = W{q,k,v}[c][m&63]
      int m = i >> 7, c = i & 127;
      int sel = m >> 6, d = m & 63;
      const float* srcp = sel == 0 ? Wq : (sel == 1 ? Wk : Wv);
      wqkvb[i] = f2bf(srcp[c * DK + d]);
      return;
    }
    i -= 24576;
    if (i < 8192) {  // wo2b[o][d] = Wo[d][o] + Wo[d+64][o]
      int o = i >> 6, d = i & 63;
      wo2b[i] = f2bf(Wo[d * CC + o] + Wo[(d + 64) * CC + o]);
      return;
    }
    i -= 8192;
    fcwb[i] = f2bf(fcw[i]);
    return;
  }
  // partials of x+pos: 512 blocks x 4 waves, one (b,c) row per wave
  int w = threadIdx.x >> 6, lane = threadIdx.x & 63;
  int bc = (blockIdx.x - 448) * 4 + w;  // 0..2047
  int c = bc & (CC - 1);
  float freq = expf(-((float)(c & ~1) * (1.f / (float)CC)) * 9.210340371976184f);
  float ph = (c & 1) ? 1.5707963267948966f : 0.f;
  const float* xr = x + (size_t)bc * TT;
  float s = 0.f, ss = 0.f;
#pragma unroll
  for (int k = 0; k < 4; ++k) {
    int t = (k * 64 + lane) * 4;
    float4 v = *(const float4*)(xr + t);
    v.x += sinf((float)(t + 0) * freq + ph);
    v.y += sinf((float)(t + 1) * freq + ph);
    v.z += sinf((float)(t + 2) * freq + ph);
    v.w += sinf((float)(t + 3) * freq + ph);
    s += v.x + v.y + v.z + v.w;
    ss += v.x * v.x + v.y * v.y + v.z * v.z + v.w * v.w;
  }
#pragma unroll
  for (int off = 32; off; off >>= 1) { s += __shfl_xor(s, off); ss += __shfl_xor(ss, off); }
  if (lane == 0) { part0[(size_t)bc * 2] = s; part0[(size_t)bc * 2 + 1] = ss; }
}

// ------- dsconv (32-col tiles, 512 threads = 8 waves): [ADD_POS] [LN-in] depthwise ->
//         MFMA pointwise + relu + [LN-res] residual; coalesced float4 out -------
template <bool LN_IN, bool LN_RES, bool ADD_POS>
__global__ __launch_bounds__(512) void k_dsconv(const float* __restrict__ in,
                                                const float* __restrict__ lng,
                                                const float* __restrict__ lnb,
                                                const float* __restrict__ part_in, int npart,
                                                const float* __restrict__ dww,
                                                const float* __restrict__ dwb,
                                                const short* __restrict__ pwwb,
                                                const float* __restrict__ pwb,
                                                float* __restrict__ out,
                                                float* __restrict__ part_out) {
  int tile = blockIdx.x & 31, b = blockIdx.x >> 5;
  int t0 = tile * 32;
  __shared__ float stats[2];
  __shared__ float xs[CC][41];                   // window t0-4 .. t0+35 (40 used)
  __shared__ float xr2[CC][33];                  // raw copy (LN_IN) then output staging
  __shared__ __align__(16) short Dt[32][136];
  ln_stats_from_parts(part_in + (size_t)b * npart * 2, npart, stats);
  float mu = stats[0], rs = stats[1];

  for (int i = threadIdx.x; i < CC * 10; i += 512) {
    int c = i / 10, q = i - c * 10;
    int tb = t0 - 4 + q * 4;
    const float* rowp = in + ((size_t)b * CC + c) * TT;
    float freq = 0.f, ph = 0.f;
    if (ADD_POS) {
      freq = expf(-((float)(c & ~1) * (1.f / (float)CC)) * 9.210340371976184f);
      ph = (c & 1) ? 1.5707963267948966f : 0.f;
    }
    float r0, r1, r2, r3, o0, o1, o2, o3;
    bool full = (tb >= 0) && (tb + 4 <= TT);
    if (full) {
      float4 v = *(const float4*)(rowp + tb);
      if (ADD_POS) {
        v.x += sinf((float)(tb + 0) * freq + ph);
        v.y += sinf((float)(tb + 1) * freq + ph);
        v.z += sinf((float)(tb + 2) * freq + ph);
        v.w += sinf((float)(tb + 3) * freq + ph);
      }
      r0 = v.x; r1 = v.y; r2 = v.z; r3 = v.w;
      o0 = r0; o1 = r1; o2 = r2; o3 = r3;
      if (LN_IN) {
        float4 g = *(const float4*)(lng + (size_t)c * TT + tb);
        float4 bv = *(const float4*)(lnb + (size_t)c * TT + tb);
        o0 = (r0 - mu) * rs * g.x + bv.x;
        o1 = (r1 - mu) * rs * g.y + bv.y;
        o2 = (r2 - mu) * rs * g.z + bv.z;
        o3 = (r3 - mu) * rs * g.w + bv.w;
      }
    } else {
      float rr[4], oo[4];
#pragma unroll
      for (int k = 0; k < 4; ++k) {
        int t = tb + k;
        bool inb = (t >= 0) && (t < TT);
        float rv = 0.f;
        if (inb) {
          rv = rowp[t];
          if (ADD_POS) rv += sinf((float)t * freq + ph);
        }
        rr[k] = rv;
        float ov = rv;
        if (LN_IN && inb)
          ov = (rv - mu) * rs * lng[(size_t)c * TT + t] + lnb[(size_t)c * TT + t];
        oo[k] = ov;
      }
      r0 = rr[0]; r1 = rr[1]; r2 = rr[2]; r3 = rr[3];
      o0 = oo[0]; o1 = oo[1]; o2 = oo[2]; o3 = oo[3];
    }
    if (LN_IN && q >= 1 && q <= 8) {
      int tl = (q - 1) * 4;
      xr2[c][tl] = r0; xr2[c][tl + 1] = r1; xr2[c][tl + 2] = r2; xr2[c][tl + 3] = r3;
    }
    int base = q * 4;
    xs[c][base] = o0; xs[c][base + 1] = o1; xs[c][base + 2] = o2; xs[c][base + 3] = o3;
  }
  __syncthreads();
  for (int i = threadIdx.x; i < 32 * CC; i += 512) {
    int t = i >> 7, c = i & 127;
    float a = dwb[c];
#pragma unroll
    for (int j = 0; j < KK; ++j) a += dww[c * KK + j] * xs[c][t + j + 1];
    Dt[t][c] = f2bf(a);
  }
  __syncthreads();

  int w = threadIdx.x >> 6, lane = threadIdx.x & 63;  // 8 waves: rows w*16..w*16+15
  int lo = lane & 15, hi = lane >> 4;
  f32x4 acc[2];
#pragma unroll
  for (int nt = 0; nt < 2; ++nt) { acc[nt][0] = 0.f; acc[nt][1] = 0.f; acc[nt][2] = 0.f; acc[nt][3] = 0.f; }
#pragma unroll
  for (int ks = 0; ks < 4; ++ks) {
    s16x8 b0 = *(const s16x8*)&Dt[lo][ks * 32 + hi * 8];
    s16x8 b1 = *(const s16x8*)&Dt[16 + lo][ks * 32 + hi * 8];
    s16x8 a0 = *(const s16x8*)&pwwb[(size_t)(w * 16 + lo) * CC + ks * 32 + hi * 8];
    acc[0] = __builtin_amdgcn_mfma_f32_16x16x32_bf16(a0, b0, acc[0], 0, 0, 0);
    acc[1] = __builtin_amdgcn_mfma_f32_16x16x32_bf16(a0, b1, acc[1], 0, 0, 0);
  }

  float s = 0.f, ss = 0.f;
#pragma unroll
  for (int nt = 0; nt < 2; ++nt)
#pragma unroll
    for (int r = 0; r < 4; ++r) {
      int row = w * 16 + hi * 4 + r;
      int tl = nt * 16 + lo;
      int t = t0 + tl;
      float v = acc[nt][r] + pwb[row];
      v = v > 0.f ? v : 0.f;
      float rv;
      if (LN_RES) {
        float raw = xs[row][tl + 4];
        rv = (raw - mu) * rs * lng[row * TT + t] + lnb[row * TT + t];
      } else if (LN_IN) {
        rv = xr2[row][tl];
      } else {
        rv = xs[row][tl + 4];
      }
      v += rv;
      xr2[row][tl] = v;
      s += v; ss += v * v;
    }
  __syncthreads();
  for (int u = threadIdx.x; u < 1024; u += 512) {
    int c = u >> 3, q = u & 7;
    float4 o4;
    o4.x = xr2[c][q * 4]; o4.y = xr2[c][q * 4 + 1];
    o4.z = xr2[c][q * 4 + 2]; o4.w = xr2[c][q * 4 + 3];
    *(float4*)(out + ((size_t)b * CC + c) * TT + t0 + q * 4) = o4;
  }
  block_partial_512(s, ss, part_out + (size_t)blockIdx.x * 2);
}

// ---------------- q,k,v projections (32-col tiles, 512 threads) ----------------
__global__ __launch_bounds__(512) void k_qkv(const float* __restrict__ in,
                                             const float* __restrict__ lng,
                                             const float* __restrict__ lnb,
                                             const float* __restrict__ part_in,
                                             const short* __restrict__ wqkvb,
                                             short* __restrict__ q,
                                             short* __restrict__ k,
                                             short* __restrict__ vt) {
  int tile = blockIdx.x & 31, b = blockIdx.x >> 5;
  int t0 = tile * 32;
  __shared__ float stats[2];
  __shared__ __align__(16) short Dt[32][136];
  __shared__ __align__(16) short stgQ[32 * 64];
  __shared__ __align__(16) short stgK[32 * 64];
  __shared__ __align__(16) short stgV[64][40];
  ln_stats_from_parts(part_in + (size_t)b * 64, 32, stats);
  float mu = stats[0], rs = stats[1];
  for (int i = threadIdx.x; i < CC * 8; i += 512) {
    int c = i >> 3, qq = i & 7;
    int t = qq * 4;
    size_t off = (size_t)c * TT + t0 + t;
    float4 v = *(const float4*)(in + (size_t)b * CC * TT + off);
    float4 g = *(const float4*)(lng + off);
    float4 bb = *(const float4*)(lnb + off);
    Dt[t + 0][c] = f2bf((v.x - mu) * rs * g.x + bb.x);
    Dt[t + 1][c] = f2bf((v.y - mu) * rs * g.y + bb.y);
    Dt[t + 2][c] = f2bf((v.z - mu) * rs * g.z + bb.z);
    Dt[t + 3][c] = f2bf((v.w - mu) * rs * g.w + bb.w);
  }
  __syncthreads();

  int w = threadIdx.x >> 6, lane = threadIdx.x & 63;  // waves 0..5 active: rows w*32..w*32+31 of 192
  int lo = lane & 15, hi = lane >> 4;
  if (w < 6) {
    f32x4 acc[2][2];
#pragma unroll
    for (int mt = 0; mt < 2; ++mt)
#pragma unroll
      for (int nt = 0; nt < 2; ++nt) { acc[mt][nt][0] = 0.f; acc[mt][nt][1] = 0.f; acc[mt][nt][2] = 0.f; acc[mt][nt][3] = 0.f; }
#pragma unroll
    for (int ks = 0; ks < 4; ++ks) {
      s16x8 b0 = *(const s16x8*)&Dt[lo][ks * 32 + hi * 8];
      s16x8 b1 = *(const s16x8*)&Dt[16 + lo][ks * 32 + hi * 8];
#pragma unroll
      for (int mt = 0; mt < 2; ++mt) {
        s16x8 a = *(const s16x8*)&wqkvb[(size_t)(w * 32 + mt * 16 + lo) * CC + ks * 32 + hi * 8];
        acc[mt][0] = __builtin_amdgcn_mfma_f32_16x16x32_bf16(a, b0, acc[mt][0], 0, 0, 0);
        acc[mt][1] = __builtin_amdgcn_mfma_f32_16x16x32_bf16(a, b1, acc[mt][1], 0, 0, 0);
      }
    }
#pragma unroll
    for (int mt = 0; mt < 2; ++mt)
#pragma unroll
      for (int nt = 0; nt < 2; ++nt) {
        int m0 = w * 32 + mt * 16 + hi * 4;
        int tl = nt * 16 + lo;
        short pv[4];
#pragma unroll
        for (int j = 0; j < 4; ++j) pv[j] = f2bf(acc[mt][nt][j]);
        if (m0 < 64) {
          *(short4*)&stgQ[tl * 64 + m0] = make_short4(pv[0], pv[1], pv[2], pv[3]);
        } else if (m0 < 128) {
          *(short4*)&stgK[tl * 64 + (m0 - 64)] = make_short4(pv[0], pv[1], pv[2], pv[3]);
        } else {
          int d = m0 - 128;
#pragma unroll
          for (int j = 0; j < 4; ++j) stgV[d + j][tl] = pv[j];
        }
      }
  }
  __syncthreads();
  {
    if (threadIdx.x < 256) {
      int t = threadIdx.x >> 3, ch = threadIdx.x & 7;   // 32 rows x 8 chunks
      *(s16x8*)(q + ((size_t)b * TT + t0 + t) * DK + ch * 8) = *(const s16x8*)&stgQ[t * 64 + ch * 8];
      int d = threadIdx.x >> 2, cv = threadIdx.x & 3;   // 64 rows x 4 chunks
      *(s16x8*)(vt + ((size_t)b * DK + d) * TT + t0 + cv * 8) = *(const s16x8*)&stgV[d][cv * 8];
    } else {
      int i = threadIdx.x - 256;
      int t = i >> 3, ch = i & 7;
      *(s16x8*)(k + ((size_t)b * TT + t0 + t) * DK + ch * 8) = *(const s16x8*)&stgK[t * 64 + ch * 8];
    }
  }
}

// ---------------- flash attention, split-K; register-double-buffered K/V staging ----------------
__global__ __launch_bounds__(128) void k_attn(const short* __restrict__ qb,
                                              const short* __restrict__ kbuf,
                                              const short* __restrict__ vtb,
                                              const float* __restrict__ mask,
                                              short* __restrict__ pacch,
                                              float* __restrict__ pml) {
  int sp = blockIdx.x & (NSPLIT - 1);
  int qt = (blockIdx.x >> 2) & 31;
  int b = blockIdx.x >> 7;
  int w = threadIdx.x >> 6, lane = threadIdx.x & 63;
  int lo = lane & 15, hi = lane >> 4;

  __shared__ __align__(16) short ks[64][72];
  __shared__ __align__(16) short vt[64][72];
  __shared__ __align__(16) short ps[2][16][68];
  __shared__ float ms[64];

  const short* qp = qb + ((size_t)b * TT + qt * 32 + w * 16 + lo) * DK + hi * 8;
  s16x8 aq0 = *(const s16x8*)qp;
  s16x8 aq1 = *(const s16x8*)(qp + 32);

  f32x4 acc[4];
  float m_i[4], l_i[4];
#pragma unroll
  for (int r = 0; r < 4; ++r) {
    m_i[r] = -3.0e38f; l_i[r] = 0.f;
#pragma unroll
    for (int nt = 0; nt < 4; ++nt) acc[nt][r] = 0.f;
  }
  const float scale = 0.125f;
  const int kb0 = sp * (TT / 64 / NSPLIT);   // 4 iterations

  s16x8 kreg[4], vreg[4];
#pragma unroll
  for (int j = 0; j < 4; ++j) {
    int i = threadIdx.x + j * 128;
    int r = i >> 3, ch = i & 7;
    kreg[j] = *(const s16x8*)(kbuf + ((size_t)b * TT + kb0 * 64 + r) * DK + ch * 8);
    vreg[j] = *(const s16x8*)(vtb + ((size_t)b * DK + r) * TT + kb0 * 64 + ch * 8);
  }

  for (int it = 0; it < 4; ++it) {
    int kb2 = kb0 + it;
    __syncthreads();
#pragma unroll
    for (int j = 0; j < 4; ++j) {
      int i = threadIdx.x + j * 128;
      int r = i >> 3, ch = i & 7;
      *(s16x8*)&ks[r][ch * 8] = kreg[j];
      *(s16x8*)&vt[r][ch * 8] = vreg[j];
    }
    if (threadIdx.x < 64) ms[threadIdx.x] = mask[(size_t)b * TT + kb2 * 64 + threadIdx.x];
    __syncthreads();
    if (it < 3) {
#pragma unroll
      for (int j = 0; j < 4; ++j) {
        int i = threadIdx.x + j * 128;
        int r = i >> 3, ch = i & 7;
        kreg[j] = *(const s16x8*)(kbuf + ((size_t)b * TT + (kb2 + 1) * 64 + r) * DK + ch * 8);
        vreg[j] = *(const s16x8*)(vtb + ((size_t)b * DK + r) * TT + (kb2 + 1) * 64 + ch * 8);
      }
    }

    f32x4 sc[4];
#pragma unroll
    for (int nt = 0; nt < 4; ++nt) {
      f32x4 z; z[0] = 0.f; z[1] = 0.f; z[2] = 0.f; z[3] = 0.f;
      s16x8 bk0 = *(const s16x8*)&ks[nt * 16 + lo][hi * 8];
      s16x8 bk1 = *(const s16x8*)&ks[nt * 16 + lo][32 + hi * 8];
      z = __builtin_amdgcn_mfma_f32_16x16x32_bf16(aq0, bk0, z, 0, 0, 0);
      z = __builtin_amdgcn_mfma_f32_16x16x32_bf16(aq1, bk1, z, 0, 0, 0);
      sc[nt] = z;
    }
#pragma unroll
    for (int nt = 0; nt < 4; ++nt) {
      float mv = ms[nt * 16 + lo];
      float addv = (1.f - mv) * -1e30f;
#pragma unroll
      for (int r = 0; r < 4; ++r) sc[nt][r] = sc[nt][r] * scale * mv + addv;
    }
    float alpha[4];
#pragma unroll
    for (int r = 0; r < 4; ++r) {
      float m0 = fmaxf(fmaxf(sc[0][r], sc[1][r]), fmaxf(sc[2][r], sc[3][r]));
#pragma unroll
      for (int off = 1; off < 16; off <<= 1) m0 = fmaxf(m0, __shfl_xor(m0, off));
      float mn = fmaxf(m_i[r], m0);
      alpha[r] = __expf(m_i[r] - mn);
      m_i[r] = mn;
    }
    float psum[4] = {0.f, 0.f, 0.f, 0.f};
#pragma unroll
    for (int nt = 0; nt < 4; ++nt)
#pragma unroll
      for (int r = 0; r < 4; ++r) {
        float p = __expf(sc[nt][r] - m_i[r]);
        psum[r] += p;
        ps[w][hi * 4 + r][nt * 16 + lo] = f2bf(p);
      }
#pragma unroll
    for (int r = 0; r < 4; ++r) {
      float sum = psum[r];
#pragma unroll
      for (int off = 1; off < 16; off <<= 1) sum += __shfl_xor(sum, off);
      l_i[r] = l_i[r] * alpha[r] + sum;
    }
#pragma unroll
    for (int nt = 0; nt < 4; ++nt)
#pragma unroll
      for (int r = 0; r < 4; ++r) acc[nt][r] *= alpha[r];

    s16x8 ap0 = *(const s16x8*)&ps[w][lo][hi * 8];
    s16x8 ap1 = *(const s16x8*)&ps[w][lo][32 + hi * 8];
#pragma unroll
    for (int nt = 0; nt < 4; ++nt) {
      s16x8 bv0 = *(const s16x8*)&vt[nt * 16 + lo][hi * 8];
      s16x8 bv1 = *(const s16x8*)&vt[nt * 16 + lo][32 + hi * 8];
      acc[nt] = __builtin_amdgcn_mfma_f32_16x16x32_bf16(ap0, bv0, acc[nt], 0, 0, 0);
      acc[nt] = __builtin_amdgcn_mfma_f32_16x16x32_bf16(ap1, bv1, acc[nt], 0, 0, 0);
    }
  }
  __syncthreads();
  short* pc = &ks[0][0];  // 32 x 64 shorts
#pragma unroll
  for (int r = 0; r < 4; ++r) {
    int row = w * 16 + hi * 4 + r;
#pragma unroll
    for (int nt = 0; nt < 4; ++nt) pc[row * 64 + nt * 16 + lo] = f2bf(acc[nt][r]);
    if (lo == 0) {
      size_t mb = (((size_t)b * TT + qt * 32 + row) * NSPLIT + sp) * 2;
      pml[mb] = m_i[r];
      pml[mb + 1] = l_i[r];
    }
  }
  __syncthreads();
  for (int u = threadIdx.x; u < 256; u += 128) {
    int row = u >> 3, ch = u & 7;
    size_t pb = (((size_t)b * TT + qt * 32 + row) * NSPLIT + sp) * DK;
    *(s16x8*)(pacch + pb + ch * 8) = *(const s16x8*)&pc[row * 64 + ch * 8];
  }
}

// ------- fused: split-K combine (LDS) + heads@Wo2 MFMA + residual (512 threads) -------
__global__ __launch_bounds__(512) void k_attnout2(const short* __restrict__ pacch,
                                                  const float* __restrict__ pml,
                                                  const float* __restrict__ mask,
                                                  const short* __restrict__ wo2b,
                                                  const float* __restrict__ res,
                                                  float* __restrict__ out,
                                                  float* __restrict__ part_out) {
  int tile = blockIdx.x & 31, b = blockIdx.x >> 5;
  int t0 = tile * 32;
  __shared__ __align__(16) short Ht[32][72];
  __shared__ float ot[128][33];
  if (threadIdx.x < 256) {
    int i = threadIdx.x;          // 32 rows x 8 chunks of 8 d
    int tr = i >> 3, q = i & 7;
    size_t rb = (size_t)b * TT + t0 + tr;
    s16x8 pvv[NSPLIT];
#pragma unroll
    for (int s = 0; s < NSPLIT; ++s)
      pvv[s] = *(const s16x8*)(pacch + (rb * NSPLIT + s) * DK + q * 8);
    float m[NSPLIT], l[NSPLIT];
#pragma unroll
    for (int s = 0; s < NSPLIT; ++s) {
      m[s] = pml[(rb * NSPLIT + s) * 2];
      l[s] = pml[(rb * NSPLIT + s) * 2 + 1];
    }
    float M = fmaxf(fmaxf(m[0], m[1]), fmaxf(m[2], m[3]));
    float wgt[NSPLIT], L = 0.f;
#pragma unroll
    for (int s = 0; s < NSPLIT; ++s) { wgt[s] = __expf(m[s] - M); L += wgt[s] * l[s]; }
    float inv = mask[rb] / L;
    float o[8] = {0.f, 0.f, 0.f, 0.f, 0.f, 0.f, 0.f, 0.f};
#pragma unroll
    for (int s = 0; s < NSPLIT; ++s) {
#pragma unroll
      for (int j = 0; j < 8; ++j) o[j] += wgt[s] * bf2f(pvv[s][j]);
    }
    short h[8];
#pragma unroll
    for (int j = 0; j < 8; ++j) h[j] = f2bf(o[j] * inv);
    *(s16x8*)&Ht[tr][q * 8] = *(const s16x8*)h;
  }
  __syncthreads();

  int w = threadIdx.x >> 6, lane = threadIdx.x & 63;  // 8 waves: rows w*16
  int lo = lane & 15, hi = lane >> 4;
  f32x4 acc[2];
#pragma unroll
  for (int nt = 0; nt < 2; ++nt) { acc[nt][0] = 0.f; acc[nt][1] = 0.f; acc[nt][2] = 0.f; acc[nt][3] = 0.f; }
#pragma unroll
  for (int ks = 0; ks < 2; ++ks) {
    s16x8 b0 = *(const s16x8*)&Ht[lo][ks * 32 + hi * 8];
    s16x8 b1 = *(const s16x8*)&Ht[16 + lo][ks * 32 + hi * 8];
    s16x8 a0 = *(const s16x8*)&wo2b[(size_t)(w * 16 + lo) * DK + ks * 32 + hi * 8];
    acc[0] = __builtin_amdgcn_mfma_f32_16x16x32_bf16(a0, b0, acc[0], 0, 0, 0);
    acc[1] = __builtin_amdgcn_mfma_f32_16x16x32_bf16(a0, b1, acc[1], 0, 0, 0);
  }
  float s = 0.f, ss = 0.f;
#pragma unroll
  for (int nt = 0; nt < 2; ++nt)
#pragma unroll
    for (int r = 0; r < 4; ++r) {
      int row = w * 16 + hi * 4 + r;
      int tl = nt * 16 + lo;
      size_t idx = ((size_t)b * CC + row) * TT + t0 + tl;
      float v = acc[nt][r] + res[idx];
      ot[row][tl] = v;
      s += v; ss += v * v;
    }
  __syncthreads();
  for (int u = threadIdx.x; u < 1024; u += 512) {
    int c = u >> 3, q = u & 7;
    float4 o4;
    o4.x = ot[c][q * 4]; o4.y = ot[c][q * 4 + 1];
    o4.z = ot[c][q * 4 + 2]; o4.w = ot[c][q * 4 + 3];
    *(float4*)(out + ((size_t)b * CC + c) * TT + t0 + q * 4) = o4;
  }
  block_partial_512(s, ss, part_out + (size_t)blockIdx.x * 2);
}

// ---------------- FC (32-col tiles, 512 threads): LN + MFMA + relu + residual ----------------
__global__ __launch_bounds__(512) void k_fc(const float* __restrict__ in,
                                            const float* __restrict__ lng,
                                            const float* __restrict__ lnb,
                                            const float* __restrict__ part_in,
                                            const short* __restrict__ fcwb,
                                            const float* __restrict__ fb,
                                            float* __restrict__ out) {
  int tile = blockIdx.x & 31, b = blockIdx.x >> 5;
  int t0 = tile * 32;
  __shared__ float stats[2];
  __shared__ float xr2[CC][33];
  __shared__ __align__(16) short Dt[32][136];
  ln_stats_from_parts(part_in + (size_t)b * 64, 32, stats);
  float mu = stats[0], rs = stats[1];
  for (int i = threadIdx.x; i < CC * 8; i += 512) {
    int c = i >> 3, q = i & 7;
    int t = q * 4;
    size_t off = (size_t)c * TT + t0 + t;
    float4 v = *(const float4*)(in + (size_t)b * CC * TT + off);
    float4 g = *(const float4*)(lng + off);
    float4 bb = *(const float4*)(lnb + off);
    xr2[c][t] = v.x; xr2[c][t + 1] = v.y; xr2[c][t + 2] = v.z; xr2[c][t + 3] = v.w;
    Dt[t + 0][c] = f2bf((v.x - mu) * rs * g.x + bb.x);
    Dt[t + 1][c] = f2bf((v.y - mu) * rs * g.y + bb.y);
    Dt[t + 2][c] = f2bf((v.z - mu) * rs * g.z + bb.z);
    Dt[t + 3][c] = f2bf((v.w - mu) * rs * g.w + bb.w);
  }
  __syncthreads();

  int w = threadIdx.x >> 6, lane = threadIdx.x & 63;  // 8 waves: rows w*16
  int lo = lane & 15, hi = lane >> 4;
  f32x4 acc[2];
#pragma unroll
  for (int nt = 0; nt < 2; ++nt) { acc[nt][0] = 0.f; acc[nt][1] = 0.f; acc[nt][2] = 0.f; acc[nt][3] = 0.f; }
#pragma unroll
  for (int ks = 0; ks < 4; ++ks) {
    s16x8 b0 = *(const s16x8*)&Dt[lo][ks * 32 + hi * 8];
    s16x8 b1 = *(const s16x8*)&Dt[16 + lo][ks * 32 + hi * 8];
    s16x8 a0 = *(const s16x8*)&fcwb[(size_t)(w * 16 + lo) * CC + ks * 32 + hi * 8];
    acc[0] = __builtin_amdgcn_mfma_f32_16x16x32_bf16(a0, b0, acc[0], 0, 0, 0);
    acc[1] = __builtin_amdgcn_mfma_f32_16x16x32_bf16(a0, b1, acc[1], 0, 0, 0);
  }
#pragma unroll
  for (int nt = 0; nt < 2; ++nt)
#pragma unroll
    for (int r = 0; r < 4; ++r) {
      int row = w * 16 + hi * 4 + r;
      int tl = nt * 16 + lo;
      float v = acc[nt][r] + fb[row];
      v = v > 0.f ? v : 0.f;
      xr2[row][tl] = v + xr2[row][tl];
    }
  __syncthreads();
  for (int u = threadIdx.x; u < 1024; u += 512) {
    int c = u >> 3, q = u & 7;
    float4 o4;
    o4.x = xr2[c][q * 4]; o4.y = xr2[c][q * 4 + 1];
    o4.z = xr2[c][q * 4 + 2]; o4.w = xr2[c][q * 4 + 3];
    *(float4*)(out + ((size_t)b * CC + c) * TT + t0 + q * 4) = o4;
  }
}

extern "C" void kernel_launch(void* const* d_in, const int* in_sizes, int n_in,
                              void* d_out, int out_size, void* d_ws, size_t ws_size,
                              hipStream_t stream) {
  const float* x    = (const float*)d_in[0];
  const float* mask = (const float*)d_in[1];
  const float* dww  = (const float*)d_in[2];
  const float* dwb  = (const float*)d_in[3];
  const float* pww  = (const float*)d_in[4];
  const float* pwb  = (const float*)d_in[5];
  const float* n0g  = (const float*)d_in[6];
  const float* n0b  = (const float*)d_in[7];
  const float* nsg  = (const float*)d_in[8];
  const float* nsb  = (const float*)d_in[9];
  const float* neg_ = (const float*)d_in[10];
  const float* neb  = (const float*)d_in[11];
  const float* Wq   = (const float*)d_in[12];
  const float* Wk   = (const float*)d_in[13];
  const float* Wv   = (const float*)d_in[14];
  const float* Wo   = (const float*)d_in[15];
  const float* fcw  = (const float*)d_in[16];
  const float* fcb  = (const float*)d_in[17];
  float* out = (float*)d_out;

  float* W = (float*)d_ws;
  const size_t NBCT = (size_t)BB * CC * TT;
  const size_t NBTD = (size_t)BB * TT * DK;
  const size_t CT = (size_t)CC * TT;
  float* O     = W;
  float* S     = W + NBCT;
  float* PART0 = W + 2 * NBCT;           // 16*128 pairs
  float* PARTS = PART0 + 4096;           // 5 stages x 16*32 pairs
  float* PML   = PARTS + 5 * 1024;       // BB*TT*NSPLIT*2
  short* QB    = (short*)(PML + (size_t)BB * TT * NSPLIT * 2);
  short* KB    = QB + NBTD;
  short* VT    = KB + NBTD;
  short* PACCH = VT + NBTD;              // BB*TT*NSPLIT*DK bf16
  short* PWWB  = PACCH + NBTD * NSPLIT;  // 4*128*128
  short* WQKVB = PWWB + 65536;           // 192*128
  short* WO2B  = WQKVB + 24576;          // 128*64
  short* FCWB  = WO2B + 8192;            // 128*128

  k_prep0<<<960, 256, 0, stream>>>(pww, Wq, Wk, Wv, Wo, fcw, x,
                                   PWWB, WQKVB, WO2B, FCWB, PART0);
  // iter0: input = x (+pos inline), residual = LN0(x+pos)
  k_dsconv<false, true, true><<<BB * 32, 512, 0, stream>>>(
      x, n0g, n0b, PART0, 128, dww, dwb, PWWB, pwb, S, PARTS);
  k_dsconv<true, false, false><<<BB * 32, 512, 0, stream>>>(
      S, nsg + 0 * CT, nsb + 0 * CT, PARTS, 32,
      dww + 1 * CC * KK, dwb + 1 * CC, PWWB + 1 * CC * CC, pwb + 1 * CC, O, PARTS + 1024);
  k_dsconv<true, false, false><<<BB * 32, 512, 0, stream>>>(
      O, nsg + 1 * CT, nsb + 1 * CT, PARTS + 1024, 32,
      dww + 2 * CC * KK, dwb + 2 * CC, PWWB + 2 * CC * CC, pwb + 2 * CC, S, PARTS + 2048);
  k_dsconv<true, false, false><<<BB * 32, 512, 0, stream>>>(
      S, nsg + 2 * CT, nsb + 2 * CT, PARTS + 2048, 32,
      dww + 3 * CC * KK, dwb + 3 * CC, PWWB + 3 * CC * CC, pwb + 3 * CC, O, PARTS + 3072);
  // qkv: input = LN_3(O)
  k_qkv<<<BB * 32, 512, 0, stream>>>(O, nsg + 3 * CT, nsb + 3 * CT, PARTS + 3072,
                                     WQKVB, QB, KB, VT);
  k_attn<<<BB * 32 * NSPLIT, 128, 0, stream>>>(QB, KB, VT, mask, PACCH, PML);
  // fused combine + attnout: residual = O raw
  k_attnout2<<<BB * 32, 512, 0, stream>>>(PACCH, PML, mask, WO2B, O, S, PARTS + 4096);
  // fc: input = LN_e(S), residual = S raw
  k_fc<<<BB * 32, 512, 0, stream>>>(S, neg_, neb, PARTS + 4096, FCWB, fcb, out);
}